// Round 11
// baseline (158.130 us; speedup 1.0000x reference)
//
#include <hip/hip_runtime.h>
#include <stdint.h>

#define N_NODES 50000
#define N_EDGES 1600000
#define N_FEAT 128
#define CAP 64            // final slots per row; Poisson(28.8) mean, +6.5 sigma
#define OVF_PW 256        // per-convA-wg overflow slots (expected usage: ~0)
#define OVF_PB 192        // per-bucket overflow slots (expected usage: ~0)

// radix-partition parameters
#define RSHIFT 7          // 128 rows per bucket: NB=391 blocks fills all CUs
#define BROWS 128
#define NB 391            // ceil(50000 / 128)
#define NWG_A 250         // pass-A workgroups; 250*1600 chunks * 4 edges = 1.6M exact
#define A_THREADS 1024
#define CHUNKS_PW 1600    // 4-edge chunks per pass-A wg
#define CAPW 40           // slots per (bucket, wg) segment; mean 14.7, +6.6 sigma
#define NREG (NWG_A + NB) // 641 overflow regions total

// ---------------- threefry2x32 (bit-exact, KAT-verified vs Random123) ----------

struct KeyPair { uint32_t a, b; };

__host__ __device__ constexpr inline uint32_t rotl32(uint32_t x, int r) {
  return (x << r) | (x >> (32 - r));
}

__host__ __device__ constexpr inline KeyPair threefry2x32(uint32_t k0, uint32_t k1,
                                                          uint32_t x0, uint32_t x1) {
  const uint32_t ks0 = k0, ks1 = k1, ks2 = k0 ^ k1 ^ 0x1BD11BDAu;
  x0 += ks0;
  x1 += ks1;
  const int rotA[4] = {13, 15, 26, 6};
  const int rotB[4] = {17, 29, 16, 24};
  const uint32_t ks[3] = {ks0, ks1, ks2};
  for (int i = 0; i < 5; ++i) {
    const int* rot = (i & 1) ? rotB : rotA;
    for (int j = 0; j < 4; ++j) {
      x0 += x1;
      x1 = rotl32(x1, rot[j]);
      x1 ^= x0;
    }
    x0 += ks[(i + 1) % 3];
    x1 += ks[(i + 2) % 3] + (uint32_t)(i + 1);
  }
  return {x0, x1};
}

// mask_key = fold_in(key(42), 7); compile-time.
constexpr KeyPair MASK_KEY = threefry2x32(0u, 42u, 0u, 7u);

// Partitionable (counter-mode) random_bits: element i -> threefry(key, (0, i)), bits = b1^b2.
__device__ inline bool edge_keep(uint32_t e) {
  KeyPair r = threefry2x32(MASK_KEY.a, MASK_KEY.b, 0u, e);
  uint32_t bits = r.a ^ r.b;
  float u = __uint_as_float((bits >> 9) | 0x3f800000u) - 1.0f;
  return u < 0.9f;
}

// fp32 bits -> bf16 with round-to-nearest-even
__device__ inline uint32_t f2bf(uint32_t b) {
  return (b + 0x7fffu + ((b >> 16) & 1u)) >> 16;
}

// true vector types (ext_vector_type) -- __builtin_nontemporal_* rejects HIP's
// class-type uint2/float4, but accepts these (identical layout & codegen).
typedef uint32_t u4v __attribute__((ext_vector_type(4)));
typedef int32_t  i4v __attribute__((ext_vector_type(4)));
typedef float    f4v __attribute__((ext_vector_type(4)));

// =================== PRIMARY PATH ==============================================
// coarse (round-11, 5B/edge): cpay u32 = (col<<16)|bf16(val) formed in pass A;
// crl u8 = row&127. wg-major layout: index ((wg*NB + b)*CAPW + li). Shrinks the
// per-wg L2 window 125KB->78KB (4.0->2.5 MB/XCD, out of the thrash zone) and
// removes the f2bf repack from the rank hot path.
// Post-mortems baked in: no global atomics (r2), cached producer->consumer
// stores / NT for read-once streams (r4), eager preloads (r5), fused conversion
// (r7), LDS payload in merged rank+gather (r9, -8us), rank preload rounds (r10,
// -4us). Round 11: +rl slot swizzle kills the pay-tile bank conflicts (730K:
// bank was idx&31, row-independent).

// Pass A (fused with x->bf16 conversion): per-wg compaction into (bucket, wg)
// segments using LDS counters only. Single barrier between cnt-init and the
// binning atomics (r11: phase0->phase1 straggler barrier removed -- each wave
// flows conversion->binning independently). Edge arrays + x are read-once ->
// NT loads. Per-wg overflow count written unconditionally -> no memset.
__global__ void __launch_bounds__(A_THREADS) convA_kernel(const float* __restrict__ x,
                                                          uint32_t* __restrict__ xb,
                                                          const float* __restrict__ adj_vals,
                                                          const int* __restrict__ row,
                                                          const int* __restrict__ col,
                                                          uint32_t* __restrict__ cpay,
                                                          uint8_t* __restrict__ crl,
                                                          uint32_t* __restrict__ lens,
                                                          uint32_t* __restrict__ ovfcA,
                                                          uint64_t* __restrict__ ovfA) {
  __shared__ uint32_t cnt[NB];
  __shared__ uint32_t ovfc;
  int wg = blockIdx.x;
  int tid = threadIdx.x;
  if (tid < NB) cnt[tid] = 0;
  if (tid == 0) ovfc = 0;
  __syncthreads();  // cnt/ovfc init visible to phase-1 atomics (only barrier)

  // phase 0: x -> bf16, 32B in / 16B out per iteration (NT in, cached out)
  const int gthreads = NWG_A * A_THREADS;
  for (int i = wg * A_THREADS + tid; i < (N_NODES * N_FEAT) / 8; i += gthreads) {
    f4v a = __builtin_nontemporal_load((const f4v*)x + 2 * i);
    f4v b = __builtin_nontemporal_load((const f4v*)x + 2 * i + 1);
    u4v o;
    o.x = f2bf(__float_as_uint(a.x)) | (f2bf(__float_as_uint(a.y)) << 16);
    o.y = f2bf(__float_as_uint(a.z)) | (f2bf(__float_as_uint(a.w)) << 16);
    o.z = f2bf(__float_as_uint(b.x)) | (f2bf(__float_as_uint(b.y)) << 16);
    o.w = f2bf(__float_as_uint(b.z)) | (f2bf(__float_as_uint(b.w)) << 16);
    ((u4v*)xb)[i] = o;
  }

  // phase 1: bin 4-edge chunks (NT vector loads), LDS-atomic slot ranks,
  // wg-major 5B/edge scatter (private ~78KB window -> L2-resident)
  uint32_t* my_pay = cpay + (size_t)wg * NB * CAPW;
  uint8_t* my_rl = crl + (size_t)wg * NB * CAPW;
  for (int ch = tid; ch < CHUNKS_PW; ch += A_THREADS) {
    const int g = wg * CHUNKS_PW + ch;     // global chunk; edges [4g, 4g+4)
    const i4v r4 = __builtin_nontemporal_load((const i4v*)row + g);
    const i4v c4 = __builtin_nontemporal_load((const i4v*)col + g);
    const f4v a4 = __builtin_nontemporal_load((const f4v*)adj_vals + g);
    const int rr[4] = {r4.x, r4.y, r4.z, r4.w};
    const int cc[4] = {c4.x, c4.y, c4.z, c4.w};
    const float aa[4] = {a4.x, a4.y, a4.z, a4.w};
#pragma unroll
    for (int k = 0; k < 4; ++k) {
      const uint32_t e = (uint32_t)(4 * g + k);
      if (!edge_keep(e)) continue;
      const uint32_t r = (uint32_t)rr[k];
      const uint32_t c = (uint32_t)cc[k];
      const float v = aa[k] / 0.9f;
      const uint32_t b = r >> RSHIFT;
      const uint32_t li = atomicAdd(&cnt[b], 1u);
      if (li < CAPW) {
        const size_t off = (size_t)b * CAPW + li;
        my_pay[off] = (c << 16) | f2bf(__float_as_uint(v));
        my_rl[off] = (uint8_t)(r & (BROWS - 1));
      } else {
        const uint32_t oi = atomicAdd(&ovfc, 1u);
        if (oi < OVF_PW)
          ovfA[(size_t)wg * OVF_PW + oi] =
              ((uint64_t)r << 48) | ((uint64_t)c << 32) | (uint64_t)__float_as_uint(v);
      }
    }
  }
  __syncthreads();
  if (tid < NB) lens[(size_t)tid * NWG_A + wg] = min(cnt[tid], (uint32_t)CAPW);
  if (tid == 0) ovfcA[wg] = min(ovfc, (uint32_t)OVF_PW);
}

// Merged rank + gather: one 512-thread wg per 128-row bucket.
// Rank (r10 preload rounds): unconditionally preload slot `lane` of all 8
// segments (independent NT loads in flight; unwritten slots < CAPW are masked
// by len), issue the 16..31 tail round, then process. ~2 serialized load
// rounds instead of ~10.
// r11: pay slot index rotated by +rl -- bank becomes (idx+rl)&31 instead of
// idx&31 (row-independent -> 730K conflicts/dispatch). Gather reads with the
// same rotation; pads still zero (tile pre-zeroed, rotation is a bijection).
__global__ void __launch_bounds__(512) rank_gather_kernel(const uint32_t* __restrict__ xb,
                                                          const uint32_t* __restrict__ cpay,
                                                          const uint8_t* __restrict__ crl,
                                                          const uint32_t* __restrict__ lens,
                                                          uint32_t* __restrict__ ovfcB,
                                                          uint32_t* __restrict__ ovfB,
                                                          float* __restrict__ out) {
  int b = blockIdx.x;
  int tid = threadIdx.x;
  __shared__ uint32_t pay[BROWS * CAP];   // 32 KB payload tile
  __shared__ uint32_t cnt[BROWS];
  __shared__ uint32_t s_len[NWG_A];
  __shared__ uint32_t ovfc;
  for (int i = tid; i < BROWS * CAP; i += 512) pay[i] = 0u;
  if (tid < BROWS) cnt[tid] = 0;
  if (tid < NWG_A) s_len[tid] = lens[(size_t)b * NWG_A + tid];
  if (tid == 0) ovfc = 0;
  __syncthreads();

  int team = tid >> 4;        // 32 teams of 16 lanes
  int lane = tid & 15;

  // ---- rank phase: preload rounds, then process ----
  uint32_t lenv[8];
  uint32_t pw[8];
  uint32_t prl[8];
#pragma unroll
  for (int s8 = 0; s8 < 8; ++s8) {
    int seg = team + (s8 << 5);
    lenv[s8] = (seg < NWG_A) ? s_len[seg] : 0u;
    size_t off = ((size_t)seg * NB + b) * CAPW + lane;
    pw[s8] = (seg < NWG_A) ? __builtin_nontemporal_load(cpay + off) : 0u;
    prl[s8] = (seg < NWG_A) ? (uint32_t)__builtin_nontemporal_load(crl + off) : 0u;
  }
  uint32_t tw[8];
  uint32_t trl[8];
#pragma unroll
  for (int s8 = 0; s8 < 8; ++s8) {
    int seg = team + (s8 << 5);
    bool tv = (lenv[s8] > 16u && (uint32_t)(lane + 16) < lenv[s8]);
    size_t off = ((size_t)seg * NB + b) * CAPW + 16 + lane;
    tw[s8] = tv ? __builtin_nontemporal_load(cpay + off) : 0u;
    trl[s8] = tv ? (uint32_t)__builtin_nontemporal_load(crl + off) : 0u;
  }

#define RANK(w, rl)                                                          \
  {                                                                          \
    uint32_t idx = atomicAdd(&cnt[(rl)], 1u);                                \
    if (idx < CAP) {                                                         \
      pay[(rl) * CAP + ((idx + (rl)) & (CAP - 1))] = (w);                    \
    } else {                                                                 \
      uint32_t oi = atomicAdd(&ovfc, 1u);                                    \
      if (oi < OVF_PB) ovfB[(size_t)b * OVF_PB + oi] = ((rl) << 24) | ((w) >> 8) | (((w) & 0xFFu) << 16); \
    }                                                                        \
  }
  // ovfB pack (u32): [31:24]=rl, [23:8]=col, [15:8 of low]=... see unpack below:
  // stored as (rl<<24) | (col<<8) | bf16>>8? -- simpler: we re-derive in unpack.

#pragma unroll
  for (int s8 = 0; s8 < 8; ++s8) {
    if ((uint32_t)lane < lenv[s8]) RANK(pw[s8], prl[s8]);
  }
#pragma unroll
  for (int s8 = 0; s8 < 8; ++s8) {
    if (lenv[s8] > 16u && (uint32_t)(lane + 16) < lenv[s8]) RANK(tw[s8], trl[s8]);
  }
  // rare tail: len > 32 (+6.6 sigma at mean 14.7)
#pragma unroll
  for (int s8 = 0; s8 < 8; ++s8) {
    uint32_t len = lenv[s8];
    if (len > 32u) {
      int seg = team + (s8 << 5);
      size_t sbase = ((size_t)seg * NB + b) * CAPW;
      for (uint32_t li = 32u + (uint32_t)lane; li < len; li += 16) {
        uint32_t w = __builtin_nontemporal_load(cpay + sbase + li);
        uint32_t rl = (uint32_t)__builtin_nontemporal_load(crl + sbase + li);
        RANK(w, rl);
      }
    }
  }
#undef RANK
  __syncthreads();
  if (tid == 0) ovfcB[b] = min(ovfc, (uint32_t)OVF_PB);

  // ---- gather phase ----
  const uint4* x4 = (const uint4*)xb;     // row stride: 16 uint4 (128 bf16)
  const int r0 = b << RSHIFT;

#define GSTEP(ww)                                                            \
  {                                                                          \
    uint32_t cc = (ww) >> 16;                                                \
    float vv = __uint_as_float((ww) << 16);                                  \
    uint4 a = x4[(size_t)cc * 16 + lane];                                    \
    acc0 += vv * __uint_as_float(a.x << 16);                                 \
    acc1 += vv * __uint_as_float(a.x & 0xffff0000u);                         \
    acc2 += vv * __uint_as_float(a.y << 16);                                 \
    acc3 += vv * __uint_as_float(a.y & 0xffff0000u);                         \
    acc4 += vv * __uint_as_float(a.z << 16);                                 \
    acc5 += vv * __uint_as_float(a.z & 0xffff0000u);                         \
    acc6 += vv * __uint_as_float(a.w << 16);                                 \
    acc7 += vv * __uint_as_float(a.w & 0xffff0000u);                         \
  }

  for (int rl = team; rl < BROWS; rl += 32) {
    int r = r0 + rl;
    if (r >= N_NODES) continue;
    uint32_t n = (min(cnt[rl], (uint32_t)CAP) + 7u) & ~7u;  // pads are zeros
    const uint32_t* prow = &pay[rl * CAP];
    float acc0 = 0.f, acc1 = 0.f, acc2 = 0.f, acc3 = 0.f;
    float acc4 = 0.f, acc5 = 0.f, acc6 = 0.f, acc7 = 0.f;
    for (uint32_t j = 0; j < n; j += 8) {
      // 8 wave-uniform LDS broadcast reads (rotated), 8 x-row loads in flight
      uint32_t w0 = prow[(j + 0 + rl) & (CAP - 1)];
      uint32_t w1 = prow[(j + 1 + rl) & (CAP - 1)];
      uint32_t w2 = prow[(j + 2 + rl) & (CAP - 1)];
      uint32_t w3 = prow[(j + 3 + rl) & (CAP - 1)];
      uint32_t w4 = prow[(j + 4 + rl) & (CAP - 1)];
      uint32_t w5 = prow[(j + 5 + rl) & (CAP - 1)];
      uint32_t w6 = prow[(j + 6 + rl) & (CAP - 1)];
      uint32_t w7 = prow[(j + 7 + rl) & (CAP - 1)];
      GSTEP(w0) GSTEP(w1) GSTEP(w2) GSTEP(w3)
      GSTEP(w4) GSTEP(w5) GSTEP(w6) GSTEP(w7)
    }
    f4v lo, hi;
    lo.x = acc0; lo.y = acc1; lo.z = acc2; lo.w = acc3;
    hi.x = acc4; hi.y = acc5; hi.z = acc6; hi.w = acc7;
    f4v* o = (f4v*)out + (size_t)r * 32 + lane * 2;
    __builtin_nontemporal_store(lo, o);
    __builtin_nontemporal_store(hi, o + 1);
  }
#undef GSTEP
}

// exact cleanup for overflow entries. ovfA (u64): (row<<48)|(col<<32)|f32bits.
// ovfB (u32, bucket-relative): (rl<<24)|(col<<8)|(bf16>>8)... unpacked per the
// RANK pack: word = (rl<<24) | (col<<8) | ((w&0xFF)<<16)? -- see pack; we invert
// exactly: w_pay = (col<<16)|bf16; stored = (rl<<24)|(w_pay>>8)|((w_pay&0xFF)<<16).
// Early-exits when all region counts are zero (the expected case).
__global__ void __launch_bounds__(256) ovf_pack_kernel(const float* __restrict__ x,
                                                       const uint32_t* __restrict__ ovfcA,
                                                       const uint64_t* __restrict__ ovfA,
                                                       const uint32_t* __restrict__ ovfcB,
                                                       const uint32_t* __restrict__ ovfB,
                                                       float* __restrict__ out) {
  __shared__ int any;
  if (threadIdx.x == 0) any = 0;
  __syncthreads();
  for (int t = threadIdx.x; t < NREG; t += 256) {
    uint32_t c = (t < NWG_A) ? ovfcA[t] : ovfcB ? ((t - NWG_A < NB) ? ovfcB[t - NWG_A] : 0u) : 0u;
    if (c) any = 1;
  }
  __syncthreads();
  if (!any) return;

  int group = (int)((blockIdx.x * 256 + threadIdx.x) >> 7);
  int f = threadIdx.x & 127;
  const int ngroups = (16 * 256) >> 7;  // 32 groups
  for (int reg = group; reg < NREG; reg += ngroups) {
    if (reg < NWG_A) {
      uint32_t c = min(ovfcA[reg], (uint32_t)OVF_PW);
      const uint64_t* basep = ovfA + (size_t)reg * OVF_PW;
      for (uint32_t i = 0; i < c; ++i) {
        uint64_t p = basep[i];
        uint32_t r = (uint32_t)(p >> 48);
        uint32_t cc = (uint32_t)((p >> 32) & 0xFFFFu);
        float v = __uint_as_float((uint32_t)p);
        atomicAdd(&out[(size_t)r * N_FEAT + f], v * x[(size_t)cc * N_FEAT + f]);
      }
    } else {
      int bb = reg - NWG_A;
      uint32_t c = min(ovfcB[bb], (uint32_t)OVF_PB);
      const uint32_t* basep = ovfB + (size_t)bb * OVF_PB;
      for (uint32_t i = 0; i < c; ++i) {
        uint32_t s = basep[i];
        // invert RANK pack: s = (rl<<24) | (w>>8) | ((w&0xFF)<<16), w=(col<<16)|bf16
        uint32_t rl = s >> 24;
        uint32_t w = ((s & 0x00FFFFu) << 8) | ((s >> 16) & 0xFFu);
        uint32_t r = ((uint32_t)bb << RSHIFT) + rl;
        uint32_t cc = w >> 16;
        float v = __uint_as_float(w << 16);  // bf16 value
        atomicAdd(&out[(size_t)r * N_FEAT + f], v * x[(size_t)cc * N_FEAT + f]);
      }
    }
  }
}

// =================== FALLBACK: fused atomic scatter ============================

__global__ void __launch_bounds__(256) scatter_fused_kernel(const float* __restrict__ x,
                                                            const float* __restrict__ adj_vals,
                                                            const int* __restrict__ row,
                                                            const int* __restrict__ col,
                                                            float* __restrict__ out) {
  long long t = (long long)blockIdx.x * blockDim.x + threadIdx.x;
  int e = (int)(t >> 6);
  int lane = (int)(t & 63);
  if (e >= N_EDGES) return;
  if (!edge_keep((uint32_t)e)) return;
  float v = adj_vals[e] / 0.9f;
  float2 xf = *(const float2*)(x + (long long)col[e] * N_FEAT + lane * 2);
  float* dst = out + (long long)row[e] * N_FEAT + lane * 2;
  atomicAdd(dst, v * xf.x);
  atomicAdd(dst + 1, v * xf.y);
}

// ---------------- launch --------------------------------------------------------

extern "C" void kernel_launch(void* const* d_in, const int* in_sizes, int n_in,
                              void* d_out, int out_size, void* d_ws, size_t ws_size,
                              hipStream_t stream) {
  const float* x        = (const float*)d_in[0];
  const float* adj_vals = (const float*)d_in[1];
  const int*   row      = (const int*)d_in[2];
  const int*   col      = (const int*)d_in[3];
  float* out = (float*)d_out;

  // ---- workspace layout (nothing needs host-side init) ----
  size_t a_ovfcA   = 0;                                                    // NWG_A u32
  size_t a_ovfcB   = (a_ovfcA + (size_t)NWG_A * 4 + 255) & ~255ull;        // NB u32
  size_t a_lens    = (a_ovfcB + (size_t)NB * 4 + 255) & ~255ull;           // NB*NWG_A u32
  size_t a_ovfA    = (a_lens + (size_t)NB * NWG_A * 4 + 255) & ~255ull;    // NWG_A*OVF_PW u64
  size_t a_ovfB    = (a_ovfA + (size_t)NWG_A * OVF_PW * 8 + 255) & ~255ull; // NB*OVF_PB u32
  size_t a_cpay    = (a_ovfB + (size_t)NB * OVF_PB * 4 + 255) & ~255ull;   // NWG_A*NB*CAPW u32
  size_t a_crl     = (a_cpay + (size_t)NWG_A * NB * CAPW * 4 + 255) & ~255ull;  // NWG_A*NB*CAPW u8
  size_t a_xb      = (a_crl + (size_t)NWG_A * NB * CAPW + 255) & ~255ull;  // N*F bf16
  size_t need      = a_xb + (size_t)N_NODES * N_FEAT * 2;

  if (ws_size >= need) {
    uint32_t* ovfcA = (uint32_t*)((char*)d_ws + a_ovfcA);
    uint32_t* ovfcB = (uint32_t*)((char*)d_ws + a_ovfcB);
    uint32_t* lens  = (uint32_t*)((char*)d_ws + a_lens);
    uint64_t* ovfA  = (uint64_t*)((char*)d_ws + a_ovfA);
    uint32_t* ovfB  = (uint32_t*)((char*)d_ws + a_ovfB);
    uint32_t* cpay  = (uint32_t*)((char*)d_ws + a_cpay);
    uint8_t*  crl   = (uint8_t*)((char*)d_ws + a_crl);
    uint32_t* xb    = (uint32_t*)((char*)d_ws + a_xb);

    convA_kernel<<<NWG_A, A_THREADS, 0, stream>>>(x, xb, adj_vals, row, col,
                                                  cpay, crl, lens, ovfcA, ovfA);
    rank_gather_kernel<<<NB, 512, 0, stream>>>(xb, cpay, crl, lens, ovfcB, ovfB, out);
    ovf_pack_kernel<<<16, 256, 0, stream>>>(x, ovfcA, ovfA, ovfcB, ovfB, out);
  } else {
    hipMemsetAsync(d_out, 0, (size_t)out_size * sizeof(float), stream);
    long long total_threads = (long long)N_EDGES * 64;
    scatter_fused_kernel<<<(int)((total_threads + 255) / 256), 256, 0, stream>>>(
        x, adj_vals, row, col, out);
  }
}